// Round 1
// baseline (553.077 us; speedup 1.0000x reference)
//
#include <hip/hip_runtime.h>
#include <hip/hip_bf16.h>
#include <cfloat>

// Problem constants (derived from reference): B=32, N=2048, D=128, K=1024
#define DIM 128
#define NCODES 1024
#define ROWS_PER_BLOCK 64
#define KSPLIT 4
#define KQ_LEN (NCODES / KSPLIT)  // 256

// latent_loss = 10*(0.25*m + m) = 12.5*m, m = mean((z_q - z_e)^2) over BN*D elems
#define LOSS_SCALE (12.5f / 8388608.0f)

// Kernel 1: ||E_k||^2 for all k -> ws
__global__ __launch_bounds__(256) void enorm_kernel(const float* __restrict__ E,
                                                    float* __restrict__ enorm,
                                                    int K) {
    int k = blockIdx.x * 256 + threadIdx.x;
    if (k < K) {
        const float* ek = E + (size_t)k * DIM;
        float a = 0.f;
#pragma unroll
        for (int d = 0; d < DIM; d += 4) {
            float4 v = *(const float4*)(ek + d);
            a += v.x * v.x + v.y * v.y + v.z * v.z + v.w * v.w;
        }
        enorm[k] = a;
    }
}

// Kernel 2: fused dist+argmin+gather+loss.
// Block = 256 threads = 4 waves. Each wave handles one quarter of the K
// codes for the block's 64 rows (thread = one row, z row in VGPRs).
// E row address is wave-uniform -> scalar loads (separate pipe from VALU).
__global__ __launch_bounds__(256) void vq_kernel(const float* __restrict__ z,
                                                 const float* __restrict__ E,
                                                 const float* __restrict__ enorm,
                                                 float* __restrict__ out,
                                                 float* __restrict__ loss) {
    const int t = threadIdx.x;
    const int lane = t & 63;
    const int kq = __builtin_amdgcn_readfirstlane(t >> 6);  // wave-uniform
    const int row = blockIdx.x * ROWS_PER_BLOCK + lane;
    const float* zrow = z + (size_t)row * DIM;

    // z row into registers (fully unrolled constant indexing -> VGPRs)
    float zr[DIM];
#pragma unroll
    for (int d = 0; d < DIM; d += 4) {
        float4 v = *(const float4*)(zrow + d);
        zr[d + 0] = v.x;
        zr[d + 1] = v.y;
        zr[d + 2] = v.z;
        zr[d + 3] = v.w;
    }

    // argmin over this wave's quarter of codes.
    // score = ||E_k||^2 - 2 z.E_k  (||z||^2 is a per-row constant, drop it)
    float best = FLT_MAX;
    int besti = 0;
    const int k0 = kq * KQ_LEN;
    for (int k = k0; k < k0 + KQ_LEN; ++k) {
        const float* ek = E + (size_t)k * DIM;  // wave-uniform -> s_load
        float a0 = 0.f, a1 = 0.f, a2 = 0.f, a3 = 0.f;
#pragma unroll
        for (int d = 0; d < DIM; d += 4) {
            a0 = fmaf(ek[d + 0], zr[d + 0], a0);
            a1 = fmaf(ek[d + 1], zr[d + 1], a1);
            a2 = fmaf(ek[d + 2], zr[d + 2], a2);
            a3 = fmaf(ek[d + 3], zr[d + 3], a3);
        }
        float dot = (a0 + a1) + (a2 + a3);
        float s = enorm[k] - 2.f * dot;
        // strict < with ascending k keeps first occurrence (jnp.argmin tie rule)
        if (s < best) {
            best = s;
            besti = k;
        }
    }

    // cross-wave argmin reduce (ascending kq + strict < keeps lowest index)
    __shared__ float sbv[KSPLIT][ROWS_PER_BLOCK];
    __shared__ int sbi[KSPLIT][ROWS_PER_BLOCK];
    __shared__ int sind[ROWS_PER_BLOCK];
    sbv[kq][lane] = best;
    sbi[kq][lane] = besti;
    __syncthreads();
    if (t < ROWS_PER_BLOCK) {
        float bv = sbv[0][t];
        int bi = sbi[0][t];
#pragma unroll
        for (int q = 1; q < KSPLIT; ++q) {
            float v = sbv[q][t];
            int i = sbi[q][t];
            if (v < bv) {
                bv = v;
                bi = i;
            }
        }
        sind[t] = bi;
    }
    __syncthreads();

    // Epilogue: coalesced gather-write of z_q (STE forward value == z_q) + loss
    const size_t obase = (size_t)blockIdx.x * (ROWS_PER_BLOCK * DIM);
    float lacc = 0.f;
#pragma unroll
    for (int i = 0; i < (ROWS_PER_BLOCK * DIM) / 256; ++i) {
        int f = t + i * 256;
        int r = f >> 7;  // DIM=128
        int d = f & (DIM - 1);
        float e = E[(size_t)sind[r] * DIM + d];
        float zv = z[obase + f];
        out[obase + f] = e;
        float dd = e - zv;
        lacc = fmaf(dd, dd, lacc);
    }
    // wave reduce then block reduce, one atomic per block
#pragma unroll
    for (int off = 32; off > 0; off >>= 1) lacc += __shfl_down(lacc, off, 64);
    __shared__ float swsum[4];
    if (lane == 0) swsum[t >> 6] = lacc;
    __syncthreads();
    if (t == 0) {
        float s = (swsum[0] + swsum[1]) + (swsum[2] + swsum[3]);
        atomicAdd(loss, s * LOSS_SCALE);
    }
}

extern "C" void kernel_launch(void* const* d_in, const int* in_sizes, int n_in,
                              void* d_out, int out_size, void* d_ws, size_t ws_size,
                              hipStream_t stream) {
    const float* z = (const float*)d_in[0];       // [BN, 128] fp32
    const float* E = (const float*)d_in[1];       // [1024, 128] fp32
    float* out = (float*)d_out;                   // [BN*128] z_q  + [1] loss
    float* enorm = (float*)d_ws;                  // K floats scratch
    const int BN = in_sizes[0] / DIM;             // 65536
    const int K = in_sizes[1] / DIM;              // 1024
    float* loss = out + (size_t)(out_size - 1);

    hipMemsetAsync(loss, 0, sizeof(float), stream);
    enorm_kernel<<<(K + 255) / 256, 256, 0, stream>>>(E, enorm, K);
    vq_kernel<<<BN / ROWS_PER_BLOCK, 256, 0, stream>>>(z, E, enorm, out, loss);
}

// Round 2
// 204.450 us; speedup vs baseline: 2.7052x; 2.7052x over previous
//
#include <hip/hip_runtime.h>
#include <hip/hip_bf16.h>
#include <cfloat>

// B=32, N=2048 -> BN=65536 rows, D=128, K=1024 codes
#define DIM 128
#define NCODES 1024
#define MTILE 128          // rows per block (4 waves x 32 rows)
#define ROWS_PER_WAVE 32
#define NSUB 2             // 16-row M-subtiles per wave
#define KSTEPS 4           // K=128 / 32
#define GROUPS (NCODES / 16)
#define LOSS_SCALE (12.5f / 8388608.0f)

typedef _Float16 f16x8 __attribute__((ext_vector_type(8)));
typedef float f32x4 __attribute__((ext_vector_type(4)));

// prep: E (fp32) -> Ehi,Elo (f16 split) + enorm = ||E_k||^2
__global__ __launch_bounds__(128) void prep_kernel(const float* __restrict__ E,
                                                   _Float16* __restrict__ Ehi,
                                                   _Float16* __restrict__ Elo,
                                                   float* __restrict__ enorm) {
    const int k = blockIdx.x;
    const int d = threadIdx.x;
    float e = E[k * DIM + d];
    _Float16 h = (_Float16)e;
    Ehi[k * DIM + d] = h;
    Elo[k * DIM + d] = (_Float16)(e - (float)h);
    float sq = e * e;
#pragma unroll
    for (int off = 32; off > 0; off >>= 1) sq += __shfl_down(sq, off, 64);
    __shared__ float s2[2];
    if ((d & 63) == 0) s2[d >> 6] = sq;
    __syncthreads();
    if (d == 0) enorm[k] = s2[0] + s2[1];
}

// Fused MFMA dist + argmin + gather + loss.
// dist'(m,k) = ||E_k||^2 - 2 z_m.E_k  via  C=enorm, A=-2z (hi/lo), B=E^T (hi/lo),
// 4 cross-product passes -> fp32-level accuracy (no argmin flips vs fp32).
__global__ __launch_bounds__(256, 2) void vq_kernel(const float* __restrict__ z,
                                                    const _Float16* __restrict__ Ehi,
                                                    const _Float16* __restrict__ Elo,
                                                    const float* __restrict__ enorm,
                                                    const float* __restrict__ E,
                                                    float* __restrict__ out,
                                                    float* __restrict__ loss) {
    const int t = threadIdx.x;
    const int lane = t & 63;
    const int wave = t >> 6;
    const int m16 = lane & 15;   // A row within subtile / B,C code col
    const int quad = lane >> 4;  // k-group for A/B; row-group for C

    __shared__ float s_enorm[NCODES];
    __shared__ float s_znorm[MTILE];
    __shared__ float s_bv[MTILE][17];
    __shared__ int s_bi[MTILE][17];
    __shared__ int s_ind[MTILE];
    __shared__ float s_wsum[4];

    for (int i = t; i < NCODES; i += 256) s_enorm[i] = enorm[i];

    // ---- A fragments: wave's 32 rows, K=128, scaled by -2, f16 hi/lo split.
    // A layout (16x16x32): lane holds A[m=lane&15][k=quad*8+j], j=0..7.
    f16x8 Ahi[NSUB][KSTEPS], Alo[NSUB][KSTEPS];
    float znp[NSUB] = {0.f, 0.f};
    const int rowbase = blockIdx.x * MTILE + wave * ROWS_PER_WAVE;
#pragma unroll
    for (int s = 0; s < NSUB; ++s) {
        const int row = rowbase + s * 16 + m16;
        const float* zp = z + (size_t)row * DIM + quad * 8;
#pragma unroll
        for (int ks = 0; ks < KSTEPS; ++ks) {
            float4 v0 = *(const float4*)(zp + ks * 32);
            float4 v1 = *(const float4*)(zp + ks * 32 + 4);
            float zv[8] = {v0.x, v0.y, v0.z, v0.w, v1.x, v1.y, v1.z, v1.w};
#pragma unroll
            for (int j = 0; j < 8; ++j) {
                znp[s] = fmaf(zv[j], zv[j], znp[s]);
                float tt = -2.f * zv[j];
                _Float16 h = (_Float16)tt;
                Ahi[s][ks][j] = h;
                Alo[s][ks][j] = (_Float16)(tt - (float)h);
            }
        }
    }
    // znorm: sum the 4 k-quads (lanes m16, m16+16, m16+32, m16+48)
#pragma unroll
    for (int s = 0; s < NSUB; ++s) {
        float v = znp[s];
        v += __shfl_xor(v, 16, 64);
        v += __shfl_xor(v, 32, 64);
        if (quad == 0) s_znorm[wave * ROWS_PER_WAVE + s * 16 + m16] = v;
    }
    __syncthreads();

    // ---- main loop over 64 groups of 16 codes
    float bestv[NSUB][4];
    int besti[NSUB][4];
#pragma unroll
    for (int s = 0; s < NSUB; ++s)
#pragma unroll
        for (int r = 0; r < 4; ++r) {
            bestv[s][r] = FLT_MAX;
            besti[s][r] = 0;
        }

    // B layout (16x16x32): lane holds B[k=quad*8+j][n=lane&15]
    const _Float16* bhp = Ehi + (size_t)m16 * DIM + quad * 8;
    const _Float16* blp = Elo + (size_t)m16 * DIM + quad * 8;

    for (int g = 0; g < GROUPS; ++g) {
        const int n = g * 16 + m16;
        const size_t boff = (size_t)g * 16 * DIM;
        f16x8 Bhi[KSTEPS], Blo[KSTEPS];
#pragma unroll
        for (int ks = 0; ks < KSTEPS; ++ks) {
            Bhi[ks] = *(const f16x8*)(bhp + boff + ks * 32);
            Blo[ks] = *(const f16x8*)(blp + boff + ks * 32);
        }
        const float e = s_enorm[n];
        f32x4 acc[NSUB];
#pragma unroll
        for (int s = 0; s < NSUB; ++s) acc[s] = (f32x4){e, e, e, e};
#pragma unroll
        for (int ks = 0; ks < KSTEPS; ++ks) {
#pragma unroll
            for (int s = 0; s < NSUB; ++s) {
                acc[s] = __builtin_amdgcn_mfma_f32_16x16x32_f16(Alo[s][ks], Blo[ks], acc[s], 0, 0, 0);
                acc[s] = __builtin_amdgcn_mfma_f32_16x16x32_f16(Ahi[s][ks], Blo[ks], acc[s], 0, 0, 0);
                acc[s] = __builtin_amdgcn_mfma_f32_16x16x32_f16(Alo[s][ks], Bhi[ks], acc[s], 0, 0, 0);
                acc[s] = __builtin_amdgcn_mfma_f32_16x16x32_f16(Ahi[s][ks], Bhi[ks], acc[s], 0, 0, 0);
            }
        }
        // C layout: col = lane&15 (code n), row = quad*4 + reg
#pragma unroll
        for (int s = 0; s < NSUB; ++s)
#pragma unroll
            for (int r = 0; r < 4; ++r) {
                float d = acc[s][r];
                if (d < bestv[s][r]) {  // strict <, ascending g => first-index tie rule
                    bestv[s][r] = d;
                    besti[s][r] = n;
                }
            }
    }

    // ---- cross-lane argmin: each row's 16 candidate lanes -> LDS
#pragma unroll
    for (int s = 0; s < NSUB; ++s)
#pragma unroll
        for (int r = 0; r < 4; ++r) {
            const int row = wave * ROWS_PER_WAVE + s * 16 + quad * 4 + r;
            s_bv[row][m16] = bestv[s][r];
            s_bi[row][m16] = besti[s][r];
        }
    __syncthreads();

    float lp = 0.f;
    if (t < MTILE) {
        float bv = s_bv[t][0];
        int bi = s_bi[t][0];
#pragma unroll
        for (int j = 1; j < 16; ++j) {
            float v = s_bv[t][j];
            int i = s_bi[t][j];
            if (v < bv || (v == bv && i < bi)) {  // lexicographic: min val, then min index
                bv = v;
                bi = i;
            }
        }
        s_ind[t] = bi;
        lp = s_znorm[t] + bv;  // ||z-E||^2 = ||z||^2 + (||E||^2 - 2 z.E)
    }
#pragma unroll
    for (int off = 32; off > 0; off >>= 1) lp += __shfl_down(lp, off, 64);
    if (lane == 0) s_wsum[wave] = lp;
    __syncthreads();
    if (t == 0)
        atomicAdd(loss, (s_wsum[0] + s_wsum[1] + s_wsum[2] + s_wsum[3]) * LOSS_SCALE);

    // ---- gather-write z_q (STE forward == z_q), float4 coalesced, E is L2-hot
    const float4* E4 = (const float4*)E;
    float4* out4 = (float4*)(out + (size_t)blockIdx.x * (MTILE * DIM));
#pragma unroll
    for (int i = 0; i < (MTILE * DIM) / (256 * 4); ++i) {
        const int f = t + i * 256;  // float4 index within tile
        const int r = f >> 5;       // 32 float4 per row
        const int d = f & 31;
        out4[f] = E4[(size_t)s_ind[r] * 32 + d];
    }
}

extern "C" void kernel_launch(void* const* d_in, const int* in_sizes, int n_in,
                              void* d_out, int out_size, void* d_ws, size_t ws_size,
                              hipStream_t stream) {
    const float* z = (const float*)d_in[0];  // [BN,128] fp32
    const float* E = (const float*)d_in[1];  // [1024,128] fp32
    float* out = (float*)d_out;              // [BN*128] z_q + [1] loss
    float* loss = out + (size_t)(out_size - 1);
    _Float16* Ehi = (_Float16*)d_ws;                 // 256 KB
    _Float16* Elo = Ehi + (size_t)NCODES * DIM;      // 256 KB
    float* enorm = (float*)(Elo + (size_t)NCODES * DIM);  // 4 KB
    const int BN = in_sizes[0] / DIM;

    hipMemsetAsync(loss, 0, sizeof(float), stream);
    prep_kernel<<<NCODES, 128, 0, stream>>>(E, Ehi, Elo, enorm);
    vq_kernel<<<BN / MTILE, 256, 0, stream>>>(z, Ehi, Elo, enorm, E, out, loss);
}